// Round 1
// baseline (383.450 us; speedup 1.0000x reference)
//
#include <hip/hip_runtime.h>
#include <hip/hip_bf16.h>

typedef __attribute__((ext_vector_type(8))) short bf16x8;
typedef __attribute__((ext_vector_type(4))) float f32x4;
typedef __attribute__((ext_vector_type(2))) float f32x2;

#define B_SZ   4096
#define K1     25
#define K2     10
#define M_L1   45056   /* B*(1+K2) */
#define D      256
#define K_DIM  512
#define N_NODES 200000

#define AS1 __attribute__((address_space(1)))
#define AS3 __attribute__((address_space(3)))

static __device__ __forceinline__ unsigned short f2bf(float f) {
    union { float f; unsigned u; } v; v.f = f;
    return (unsigned short)((v.u + 0x7fffu + ((v.u >> 16) & 1u)) >> 16);
}
static __device__ __forceinline__ float bf2f(unsigned short h) {
    union { unsigned u; float f; } v; v.u = ((unsigned)h) << 16;
    return v.f;
}

// ---- convert features fp32 -> fp8 e4m3 (51.2M elems) + W1/W2 -> bf16, one pass ----
__global__ __launch_bounds__(256)
void convert_all(const float* __restrict__ f, unsigned* __restrict__ f8,
                 const float* __restrict__ W1, const float* __restrict__ W2,
                 unsigned short* __restrict__ W1b, unsigned short* __restrict__ W2b) {
    const size_t i = ((size_t)blockIdx.x * 256 + threadIdx.x) * 8;
    const float4 a = *(const float4*)(f + i);
    const float4 b = *(const float4*)(f + i + 4);
    unsigned u0 = 0, u1 = 0;
    u0 = __builtin_amdgcn_cvt_pk_fp8_f32(a.x, a.y, u0, false);
    u0 = __builtin_amdgcn_cvt_pk_fp8_f32(a.z, a.w, u0, true);
    u1 = __builtin_amdgcn_cvt_pk_fp8_f32(b.x, b.y, u1, false);
    u1 = __builtin_amdgcn_cvt_pk_fp8_f32(b.z, b.w, u1, true);
    uint2 r; r.x = u0; r.y = u1;
    *(uint2*)(f8 + (i >> 2)) = r;
    const int j = blockIdx.x * 256 + threadIdx.x;
    if (j < D * K_DIM) {           // 131072 = 256*512 elements each
        W1b[j] = f2bf(W1[j]);
        W2b[j] = f2bf(W2[j]);
    }
}

// ---- layer-1 gather + mean: agg from fp8 table, self from fp32 features ----
__global__ __launch_bounds__(256)
void agg1_kernel(const float* __restrict__ feat,
                 const unsigned* __restrict__ f8,
                 const int* __restrict__ nodes_batch,
                 const int* __restrict__ neigh2,
                 const int* __restrict__ neigh1,
                 unsigned short* __restrict__ X1) {
    const int wave = threadIdx.x >> 6;
    const int lane = threadIdx.x & 63;
    const int m = (blockIdx.x << 2) + wave;
    const int self_node = (m < B_SZ) ? nodes_batch[m] : neigh2[m - B_SZ];
    const int* nb = neigh1 + (size_t)m * K1;

    int idxv = (lane < K1) ? nb[lane] : 0;
    const float4 s = *(const float4*)(feat + (size_t)self_node * D + (lane << 2));

    unsigned q[K1];
    #pragma unroll
    for (int j = 0; j < K1; ++j) {
        const int node = __shfl(idxv, j);
        q[j] = f8[(size_t)node * (D / 4) + lane];
    }

    float a0 = 0.f, a1 = 0.f, a2 = 0.f, a3 = 0.f;
    #pragma unroll
    for (int j = 0; j < K1; ++j) {
        const f32x2 lo = __builtin_amdgcn_cvt_pk_f32_fp8(q[j], false);
        const f32x2 hi = __builtin_amdgcn_cvt_pk_f32_fp8(q[j], true);
        a0 += lo.x; a1 += lo.y; a2 += hi.x; a3 += hi.y;
    }
    const float inv = 1.0f / (float)K1;

    unsigned short* xr = X1 + (size_t)m * K_DIM;
    *(ushort4*)(xr + (lane << 2)) =
        make_ushort4(f2bf(s.x), f2bf(s.y), f2bf(s.z), f2bf(s.w));
    *(ushort4*)(xr + D + (lane << 2)) =
        make_ushort4(f2bf(a0 * inv), f2bf(a1 * inv), f2bf(a2 * inv), f2bf(a3 * inv));
}

// ---- layer-2 build: X2[b] = [ h1[b] | mean_k h1[B + b*K2 + k] ] (bf16) ----
__global__ __launch_bounds__(256)
void agg2_kernel(const unsigned short* __restrict__ h1,
                 unsigned short* __restrict__ X2) {
    const int wave = threadIdx.x >> 6;
    const int lane = threadIdx.x & 63;
    const int b = (blockIdx.x << 2) + wave;
    const ushort4 s = *(const ushort4*)(h1 + (size_t)b * D + (lane << 2));
    float sx = 0.f, sy = 0.f, sz = 0.f, sw = 0.f;
    #pragma unroll
    for (int k = 0; k < K2; ++k) {
        const ushort4 v = *(const ushort4*)(h1 + (size_t)(B_SZ + b * K2 + k) * D + (lane << 2));
        sx += bf2f(v.x); sy += bf2f(v.y); sz += bf2f(v.z); sw += bf2f(v.w);
    }
    const float inv = 1.0f / (float)K2;
    unsigned short* xr = X2 + (size_t)b * K_DIM;
    *(ushort4*)(xr + (lane << 2)) = s;
    *(ushort4*)(xr + D + (lane << 2)) =
        make_ushort4(f2bf(sx * inv), f2bf(sy * inv), f2bf(sz * inv), f2bf(sw * inv));
}

// ---- C[M,256] = relu(A[M,512] @ W[256,512]^T) ----
// BN = 256 (full N): A rows fetched exactly once. BK=64, 8 K-steps.
// Double-buffered LDS + 2-phase pipeline (T3-minimum): issue stage(t+1),
// compute(t), then vmcnt(0)+barrier — loads stay in flight under the MFMA
// phase; one barrier per K-step instead of two.
// XOR swizzle unchanged: 16B chunk c of row r stored at slot c^(r&7); staging
// stays lane-contiguous in LDS (global_load_lds wave-uniform base + lane*16),
// swizzle applied on the per-lane *global* source address.
// Each wave computes all BM rows x its own 64-col slice (wn = w*64).
template<int BM, bool OUT_BF16>
__global__ __launch_bounds__(256)
void gemm_relu(const unsigned short* __restrict__ A,
               const unsigned short* __restrict__ W,
               void* __restrict__ Cout) {
    constexpr int MFR = BM / 16;     // M fragments per wave
    constexpr int ACALLS = BM / 8;   // global_load_lds calls for A per K-step
    __shared__ unsigned short As[2][BM * 64];
    __shared__ unsigned short Bs[2][256 * 64];
    const int tid  = threadIdx.x;
    const int w    = tid >> 6, lane = tid & 63;
    const int quad = lane >> 4, l16 = lane & 15;
    const int wn   = w << 6;
    const size_t row0 = (size_t)blockIdx.x * BM;

    // staging: one call = 1024 B = 8 LDS rows of 64 elems (128 B each)
    const int srow   = lane >> 3;                 // row within the call's 8
    const int schunk = ((lane & 7) ^ srow) << 3;  // swizzled 16B chunk (elems)
    const unsigned short* aG = A + (row0 + srow) * K_DIM + schunk;
    const unsigned short* bG = W + (size_t)srow * K_DIM + schunk;

    f32x4 acc[MFR][4];
    #pragma unroll
    for (int i = 0; i < MFR; ++i)
        #pragma unroll
        for (int j = 0; j < 4; ++j)
            acc[i][j] = (f32x4){0.f, 0.f, 0.f, 0.f};

    auto stage = [&](int buf, int k0) {
        #pragma unroll
        for (int c = w; c < ACALLS; c += 4)
            __builtin_amdgcn_global_load_lds(
                (const AS1 void*)(aG + (size_t)(c * 8) * K_DIM + k0),
                (AS3 void*)(&As[buf][c * 512]), 16, 0, 0);
        #pragma unroll
        for (int c = w; c < 32; c += 4)
            __builtin_amdgcn_global_load_lds(
                (const AS1 void*)(bG + (size_t)(c * 8) * K_DIM + k0),
                (AS3 void*)(&Bs[buf][c * 512]), 16, 0, 0);
    };

    auto compute = [&](int buf) {
        #pragma unroll
        for (int ks = 0; ks < 2; ++ks) {
            bf16x8 af[MFR], bfr[4];
            #pragma unroll
            for (int i = 0; i < MFR; ++i) {
                const int row = i * 16 + l16;
                af[i] = *(const bf16x8*)&As[buf][row * 64 + ((((ks << 2) + quad) ^ (l16 & 7)) << 3)];
            }
            #pragma unroll
            for (int i = 0; i < 4; ++i) {
                const int row = wn + i * 16 + l16;
                bfr[i] = *(const bf16x8*)&Bs[buf][row * 64 + ((((ks << 2) + quad) ^ (l16 & 7)) << 3)];
            }
            #pragma unroll
            for (int mi = 0; mi < MFR; ++mi)
                #pragma unroll
                for (int ni = 0; ni < 4; ++ni)
                    acc[mi][ni] = __builtin_amdgcn_mfma_f32_16x16x32_bf16(
                        af[mi], bfr[ni], acc[mi][ni], 0, 0, 0);
        }
    };

    stage(0, 0);
    asm volatile("s_waitcnt vmcnt(0)" ::: "memory");
    __syncthreads();
    #pragma unroll
    for (int t = 0; t < 7; ++t) {
        stage((t & 1) ^ 1, (t + 1) << 6);   // issue next tile's loads first
        compute(t & 1);                      // MFMA overlaps the loads
        asm volatile("s_waitcnt vmcnt(0)" ::: "memory");
        __syncthreads();
    }
    compute(1);                              // t=7 tile, staged at t=6

    #pragma unroll
    for (int mi = 0; mi < MFR; ++mi) {
        #pragma unroll
        for (int ni = 0; ni < 4; ++ni) {
            #pragma unroll
            for (int r = 0; r < 4; ++r) {
                const size_t gm = row0 + mi * 16 + quad * 4 + r;
                const size_t gn = (size_t)wn + ni * 16 + l16;
                float v = acc[mi][ni][r];
                v = v > 0.f ? v : 0.f;
                if (OUT_BF16)
                    ((unsigned short*)Cout)[gm * D + gn] = f2bf(v);
                else
                    ((float*)Cout)[gm * D + gn] = v;
            }
        }
    }
}

extern "C" void kernel_launch(void* const* d_in, const int* in_sizes, int n_in,
                              void* d_out, int out_size, void* d_ws, size_t ws_size,
                              hipStream_t stream) {
    const float* feat        = (const float*)d_in[0];
    const float* W1          = (const float*)d_in[1];
    const float* W2          = (const float*)d_in[2];
    const int*   nodes_batch = (const int*)d_in[3];
    const int*   neigh2      = (const int*)d_in[4];
    const int*   neigh1      = (const int*)d_in[5];
    float* out = (float*)d_out;

    char* ws = (char*)d_ws;
    unsigned*       f8   = (unsigned*)(ws);                              // 51,200,000 B
    unsigned short* X1   = (unsigned short*)(ws + 51200000);             // 46,137,344 B
    unsigned short* h1   = (unsigned short*)(ws + 51200000 + 46137344);  // 23,068,672 B
    unsigned short* X2   = (unsigned short*)(ws + 51200000 + 46137344 + 23068672); // 4,194,304 B
    unsigned short* W1b  = (unsigned short*)(ws + 51200000 + 46137344 + 23068672 + 4194304);
    unsigned short* W2b  = (unsigned short*)(ws + 51200000 + 46137344 + 23068672 + 4194304 + 262144);

    convert_all<<<25000, 256, 0, stream>>>(feat, f8, W1, W2, W1b, W2b);
    agg1_kernel<<<M_L1 / 4, 256, 0, stream>>>(feat, f8, nodes_batch, neigh2, neigh1, X1);
    gemm_relu<64, true><<<M_L1 / 64, 256, 0, stream>>>(X1, W1b, h1);
    agg2_kernel<<<B_SZ / 4, 256, 0, stream>>>(h1, X2);
    gemm_relu<16, false><<<B_SZ / 16, 256, 0, stream>>>(X2, W2b, out);
}

// Round 2
// 365.443 us; speedup vs baseline: 1.0493x; 1.0493x over previous
//
#include <hip/hip_runtime.h>
#include <hip/hip_bf16.h>

typedef __attribute__((ext_vector_type(8))) short bf16x8;
typedef __attribute__((ext_vector_type(4))) float f32x4;
typedef __attribute__((ext_vector_type(2))) float f32x2;

#define B_SZ   4096
#define K1     25
#define K2     10
#define M_L1   45056   /* B*(1+K2) */
#define D      256
#define K_DIM  512
#define N_NODES 200000

#define AS1 __attribute__((address_space(1)))
#define AS3 __attribute__((address_space(3)))

static __device__ __forceinline__ unsigned short f2bf(float f) {
    union { float f; unsigned u; } v; v.f = f;
    return (unsigned short)((v.u + 0x7fffu + ((v.u >> 16) & 1u)) >> 16);
}
static __device__ __forceinline__ float bf2f(unsigned short h) {
    union { unsigned u; float f; } v; v.u = ((unsigned)h) << 16;
    return v.f;
}

// ---- convert features fp32 -> fp8 e4m3 (51.2M elems) + W1/W2 -> bf16, one pass ----
__global__ __launch_bounds__(256)
void convert_all(const float* __restrict__ f, unsigned* __restrict__ f8,
                 const float* __restrict__ W1, const float* __restrict__ W2,
                 unsigned short* __restrict__ W1b, unsigned short* __restrict__ W2b) {
    const size_t i = ((size_t)blockIdx.x * 256 + threadIdx.x) * 8;
    const float4 a = *(const float4*)(f + i);
    const float4 b = *(const float4*)(f + i + 4);
    unsigned u0 = 0, u1 = 0;
    u0 = __builtin_amdgcn_cvt_pk_fp8_f32(a.x, a.y, u0, false);
    u0 = __builtin_amdgcn_cvt_pk_fp8_f32(a.z, a.w, u0, true);
    u1 = __builtin_amdgcn_cvt_pk_fp8_f32(b.x, b.y, u1, false);
    u1 = __builtin_amdgcn_cvt_pk_fp8_f32(b.z, b.w, u1, true);
    uint2 r; r.x = u0; r.y = u1;
    *(uint2*)(f8 + (i >> 2)) = r;
    const int j = blockIdx.x * 256 + threadIdx.x;
    if (j < D * K_DIM) {           // 131072 = 256*512 elements each
        W1b[j] = f2bf(W1[j]);
        W2b[j] = f2bf(W2[j]);
    }
}

// ============================================================================
// fused_l1: agg1 (gather+mean -> LDS A-tile, bf16) + GEMM1 + relu -> h1 (bf16)
//   grid 704 x 512 threads. LDS: As 64KB (full K=512) + Bs 2x32KB = 128KB.
//   A never touches HBM. B-tile t=0 is issued BEFORE the gather phase so the
//   W loads fly under the gather latency; K-loop is the 2-phase pipeline
//   (stage t+1, compute t, vmcnt(0)+barrier).
//   A LDS swizzle: 16B chunk c of row r stored at chunk c^(r&7) (low-3-bit
//   XOR) -> fragment ds_read_b128 is 2-way (free); gather ds_writes are
//   row-uniform so near-conflict-free.
// ============================================================================
__global__ __launch_bounds__(512)
void fused_l1(const float* __restrict__ feat,
              const unsigned* __restrict__ f8,
              const int* __restrict__ nodes_batch,
              const int* __restrict__ neigh2,
              const int* __restrict__ neigh1,
              const unsigned short* __restrict__ W,
              unsigned short* __restrict__ h1) {
    __shared__ unsigned short As[64 * 512];      // 64 KB
    __shared__ unsigned short Bs[2][256 * 64];   // 64 KB
    const int tid  = threadIdx.x;
    const int w    = tid >> 6, lane = tid & 63;
    const int quad = lane >> 4, l16 = lane & 15;
    const size_t row0 = (size_t)blockIdx.x * 64;

    // B staging: one call = 8 rows x 64 elems (1KB); swizzle on global source
    const int srow   = lane >> 3;
    const int schunk = ((lane & 7) ^ srow) << 3;
    const unsigned short* bG = W + (size_t)srow * K_DIM + schunk;

    // issue B-tile for k0=0 now; it completes under the gather phase
    #pragma unroll
    for (int c = w; c < 32; c += 8)
        __builtin_amdgcn_global_load_lds(
            (const AS1 void*)(bG + (size_t)(c * 8) * K_DIM),
            (AS3 void*)(&Bs[0][c * 512]), 16, 0, 0);

    // ---- gather + mean -> As ----
    #pragma unroll 2
    for (int rr = 0; rr < 8; ++rr) {
        const int r = (w << 3) + rr;
        const int m = (int)row0 + r;
        const int self_node = (m < B_SZ) ? nodes_batch[m] : neigh2[m - B_SZ];
        const int* nb = neigh1 + (size_t)m * K1;
        int idxv = (lane < K1) ? nb[lane] : 0;
        const float4 s = *(const float4*)(feat + (size_t)self_node * D + (lane << 2));
        unsigned q[K1];
        #pragma unroll
        for (int j = 0; j < K1; ++j) {
            const int node = __shfl(idxv, j);
            q[j] = f8[(size_t)node * (D / 4) + lane];
        }
        float a0 = 0.f, a1 = 0.f, a2 = 0.f, a3 = 0.f;
        #pragma unroll
        for (int j = 0; j < K1; ++j) {
            const f32x2 lo = __builtin_amdgcn_cvt_pk_f32_fp8(q[j], false);
            const f32x2 hi = __builtin_amdgcn_cvt_pk_f32_fp8(q[j], true);
            a0 += lo.x; a1 += lo.y; a2 += hi.x; a3 += hi.y;
        }
        const float inv = 1.0f / (float)K1;
        const int e0 = lane << 2;                  // self elems [0,256)
        const int p0 = (e0 >> 3) ^ (r & 7);
        *(ushort4*)&As[r * 512 + (p0 << 3) + (e0 & 7)] =
            make_ushort4(f2bf(s.x), f2bf(s.y), f2bf(s.z), f2bf(s.w));
        const int e1 = D + (lane << 2);            // agg elems [256,512)
        const int p1 = (e1 >> 3) ^ (r & 7);
        *(ushort4*)&As[r * 512 + (p1 << 3) + (e1 & 7)] =
            make_ushort4(f2bf(a0 * inv), f2bf(a1 * inv), f2bf(a2 * inv), f2bf(a3 * inv));
    }

    asm volatile("s_waitcnt vmcnt(0)" ::: "memory");
    __syncthreads();

    // ---- GEMM: 8 waves = 2M x 4N; each wave 32 rows x 64 cols ----
    const int wm = (w >> 2) << 5;   // 0 / 32
    const int wn = (w & 3) << 6;    // 0,64,128,192
    f32x4 acc[2][4];
    #pragma unroll
    for (int i = 0; i < 2; ++i)
        #pragma unroll
        for (int j = 0; j < 4; ++j)
            acc[i][j] = (f32x4){0.f, 0.f, 0.f, 0.f};

    for (int t = 0; t < 8; ++t) {
        if (t < 7) {
            #pragma unroll
            for (int c = w; c < 32; c += 8)
                __builtin_amdgcn_global_load_lds(
                    (const AS1 void*)(bG + (size_t)(c * 8) * K_DIM + ((t + 1) << 6)),
                    (AS3 void*)(&Bs[(t + 1) & 1][c * 512]), 16, 0, 0);
        }
        #pragma unroll
        for (int ks = 0; ks < 2; ++ks) {
            bf16x8 af[2], bfr[4];
            #pragma unroll
            for (int i = 0; i < 2; ++i) {
                const int row = wm + i * 16 + l16;
                const int ch  = (t << 3) + (ks << 2) + quad;   // 16B chunk in [0,64)
                af[i] = *(const bf16x8*)&As[row * 512 + ((ch ^ (row & 7)) << 3)];
            }
            #pragma unroll
            for (int i = 0; i < 4; ++i) {
                const int row = wn + i * 16 + l16;
                bfr[i] = *(const bf16x8*)&Bs[t & 1][row * 64 + ((((ks << 2) + quad) ^ (l16 & 7)) << 3)];
            }
            #pragma unroll
            for (int mi = 0; mi < 2; ++mi)
                #pragma unroll
                for (int ni = 0; ni < 4; ++ni)
                    acc[mi][ni] = __builtin_amdgcn_mfma_f32_16x16x32_bf16(
                        af[mi], bfr[ni], acc[mi][ni], 0, 0, 0);
        }
        asm volatile("s_waitcnt vmcnt(0)" ::: "memory");
        __syncthreads();
    }

    #pragma unroll
    for (int mi = 0; mi < 2; ++mi)
        #pragma unroll
        for (int ni = 0; ni < 4; ++ni)
            #pragma unroll
            for (int rg = 0; rg < 4; ++rg) {
                const size_t gm = row0 + wm + mi * 16 + quad * 4 + rg;
                const size_t gn = (size_t)wn + ni * 16 + l16;
                float v = acc[mi][ni][rg];
                v = v > 0.f ? v : 0.f;
                h1[gm * D + gn] = f2bf(v);
            }
}

// ============================================================================
// fused_l2: agg2 (h1 self + mean of K2 h1 rows -> LDS A-tile) + GEMM2 + relu
//   grid 256 x 256 threads, BM=16. LDS: As 16KB + Bs 2x32KB = 80KB
//   (2 blocks/CU). All 256 CUs busy (old gemm2 grid was 64 blocks).
// ============================================================================
__global__ __launch_bounds__(256)
void fused_l2(const unsigned short* __restrict__ h1,
              const unsigned short* __restrict__ W,
              float* __restrict__ out) {
    __shared__ unsigned short As[16 * 512];      // 16 KB
    __shared__ unsigned short Bs[2][256 * 64];   // 64 KB
    const int tid  = threadIdx.x;
    const int w    = tid >> 6, lane = tid & 63;
    const int quad = lane >> 4, l16 = lane & 15;
    const size_t row0 = (size_t)blockIdx.x * 16;

    const int srow   = lane >> 3;
    const int schunk = ((lane & 7) ^ srow) << 3;
    const unsigned short* bG = W + (size_t)srow * K_DIM + schunk;

    #pragma unroll
    for (int c = w; c < 32; c += 4)
        __builtin_amdgcn_global_load_lds(
            (const AS1 void*)(bG + (size_t)(c * 8) * K_DIM),
            (AS3 void*)(&Bs[0][c * 512]), 16, 0, 0);

    // ---- build A-tile: [h1[b] | mean_k h1[B + b*K2 + k]] ----
    #pragma unroll
    for (int rr = 0; rr < 4; ++rr) {
        const int r = (w << 2) + rr;
        const size_t b = row0 + r;
        const ushort4 sv = *(const ushort4*)&h1[b * D + (lane << 2)];
        float a0 = 0.f, a1 = 0.f, a2 = 0.f, a3 = 0.f;
        #pragma unroll
        for (int k = 0; k < K2; ++k) {
            const ushort4 v = *(const ushort4*)&h1[(size_t)(B_SZ + b * K2 + k) * D + (lane << 2)];
            a0 += bf2f(v.x); a1 += bf2f(v.y); a2 += bf2f(v.z); a3 += bf2f(v.w);
        }
        const float inv = 1.0f / (float)K2;
        const int e0 = lane << 2;
        const int p0 = (e0 >> 3) ^ (r & 7);
        *(ushort4*)&As[r * 512 + (p0 << 3) + (e0 & 7)] = sv;   // self: already bf16
        const int e1 = D + (lane << 2);
        const int p1 = (e1 >> 3) ^ (r & 7);
        *(ushort4*)&As[r * 512 + (p1 << 3) + (e1 & 7)] =
            make_ushort4(f2bf(a0 * inv), f2bf(a1 * inv), f2bf(a2 * inv), f2bf(a3 * inv));
    }

    asm volatile("s_waitcnt vmcnt(0)" ::: "memory");
    __syncthreads();

    const int wn = w << 6;          // each wave: all 16 rows x its 64-col slice
    f32x4 acc[4];
    #pragma unroll
    for (int j = 0; j < 4; ++j) acc[j] = (f32x4){0.f, 0.f, 0.f, 0.f};

    for (int t = 0; t < 8; ++t) {
        if (t < 7) {
            #pragma unroll
            for (int c = w; c < 32; c += 4)
                __builtin_amdgcn_global_load_lds(
                    (const AS1 void*)(bG + (size_t)(c * 8) * K_DIM + ((t + 1) << 6)),
                    (AS3 void*)(&Bs[(t + 1) & 1][c * 512]), 16, 0, 0);
        }
        #pragma unroll
        for (int ks = 0; ks < 2; ++ks) {
            const int ch = (t << 3) + (ks << 2) + quad;
            const bf16x8 af = *(const bf16x8*)&As[l16 * 512 + ((ch ^ (l16 & 7)) << 3)];
            bf16x8 bfr[4];
            #pragma unroll
            for (int i = 0; i < 4; ++i) {
                const int row = wn + i * 16 + l16;
                bfr[i] = *(const bf16x8*)&Bs[t & 1][row * 64 + ((((ks << 2) + quad) ^ (l16 & 7)) << 3)];
            }
            #pragma unroll
            for (int ni = 0; ni < 4; ++ni)
                acc[ni] = __builtin_amdgcn_mfma_f32_16x16x32_bf16(af, bfr[ni], acc[ni], 0, 0, 0);
        }
        asm volatile("s_waitcnt vmcnt(0)" ::: "memory");
        __syncthreads();
    }

    #pragma unroll
    for (int ni = 0; ni < 4; ++ni)
        #pragma unroll
        for (int rg = 0; rg < 4; ++rg) {
            const size_t gm = row0 + quad * 4 + rg;
            const size_t gn = (size_t)wn + ni * 16 + l16;
            float v = acc[ni][rg];
            out[gm * D + gn] = v > 0.f ? v : 0.f;
        }
}

extern "C" void kernel_launch(void* const* d_in, const int* in_sizes, int n_in,
                              void* d_out, int out_size, void* d_ws, size_t ws_size,
                              hipStream_t stream) {
    const float* feat        = (const float*)d_in[0];
    const float* W1          = (const float*)d_in[1];
    const float* W2          = (const float*)d_in[2];
    const int*   nodes_batch = (const int*)d_in[3];
    const int*   neigh2      = (const int*)d_in[4];
    const int*   neigh1      = (const int*)d_in[5];
    float* out = (float*)d_out;

    char* ws = (char*)d_ws;
    unsigned*       f8  = (unsigned*)(ws);                    // 51,200,000 B
    unsigned short* h1  = (unsigned short*)(ws + 51200000);   // 23,068,672 B
    unsigned short* W1b = (unsigned short*)(ws + 51200000 + 23068672);           // 262,144 B
    unsigned short* W2b = (unsigned short*)(ws + 51200000 + 23068672 + 262144);  // 262,144 B

    convert_all<<<25000, 256, 0, stream>>>(feat, f8, W1, W2, W1b, W2b);
    fused_l1<<<M_L1 / 64, 512, 0, stream>>>(feat, f8, nodes_batch, neigh2, neigh1, W1b, h1);
    fused_l2<<<B_SZ / 16, 256, 0, stream>>>(h1, W2b, out);
}